// Round 7
// baseline (2835.731 us; speedup 1.0000x reference)
//
#include <hip/hip_runtime.h>
#include <math.h>
#include <stdint.h>

#define B_SZ 32
#define T_LEN 2048
#define I_DIM 128
#define H_DIM 256
#define ROWS 32   // rows per workgroup in the two GEMM kernels

// 16-way literal repetition
#define REP16(M) M(0)M(1)M(2)M(3)M(4)M(5)M(6)M(7)M(8)M(9)M(10)M(11)M(12)M(13)M(14)M(15)
#define REP8A(M) M(0)M(1)M(2)M(3)M(4)M(5)M(6)M(7)
#define REP8B(M) M(8)M(9)M(10)M(11)M(12)M(13)M(14)M(15)

__device__ __forceinline__ float fast_tanh(float y) {
    // tanh(y) = 1 - 2/(e^{2y}+1); saturates correctly for |y| large
    float e = __expf(2.f * y);
    return 1.f - 2.f / (e + 1.f);
}

// ---------------------------------------------------------------------------
// Phase 1: xB[r][j] = sum_k x[r][k] * Bm[k][j]  (R2 version: LDS-staged x)
// ---------------------------------------------------------------------------
__global__ __launch_bounds__(256) void xb_proj(const float* __restrict__ x,
                                               const float* __restrict__ Bm,
                                               float* __restrict__ xB) {
    __shared__ float4 xt[ROWS][I_DIM / 4 + 1];
    const int tid = threadIdx.x;
    const int j = tid;
    const long r0 = (long)blockIdx.x * ROWS;

    const float4* xg = (const float4*)(x + r0 * I_DIM);
#pragma unroll
    for (int i = 0; i < 4; ++i) {
        int f = tid + i * 256;
        int rr = f >> 5;
        int kg = f & 31;
        xt[rr][kg] = xg[rr * 32 + kg];
    }
    __syncthreads();

    float acc[ROWS];
#pragma unroll
    for (int r = 0; r < ROWS; ++r) acc[r] = 0.f;

    for (int k = 0; k < I_DIM; k += 4) {
        float w0 = Bm[(k + 0) * H_DIM + j];
        float w1 = Bm[(k + 1) * H_DIM + j];
        float w2 = Bm[(k + 2) * H_DIM + j];
        float w3 = Bm[(k + 3) * H_DIM + j];
#pragma unroll
        for (int r = 0; r < ROWS; ++r) {
            float4 hv = xt[r][k >> 2];
            acc[r] = fmaf(hv.x, w0, acc[r]);
            acc[r] = fmaf(hv.y, w1, acc[r]);
            acc[r] = fmaf(hv.z, w2, acc[r]);
            acc[r] = fmaf(hv.w, w3, acc[r]);
        }
    }
#pragma unroll
    for (int r = 0; r < ROWS; ++r)
        xB[(r0 + r) * H_DIM + j] = acc[r];
}

// ---------------------------------------------------------------------------
// Phase 2: recurrence. 512 threads (8 waves) per chain.
// Thread = (wave w = tid>>6, cc = lane>>2, g = lane&3):
//   owns cols c0 = w*16+cc and c1 = c0+128, k-slice [64g, 64g+64).
//   A fragment = 32 named+pinned float4s (128 VGPRs).
// h double-buffered in LDS (2 x 1KB). Reads are XOR-swizzled:
//   addr(K) = (B + 272g) ^ 16K = B + 256g + 16*(g^K)
//   -> for fixed K the 4 g-addresses hit disjoint bank quads: conflict-free.
//   A regs loaded in the same permuted order so the dot product matches.
// Reduce: __shfl_xor masks 1,2 within the quad (VALU DPP, not LDS pipe).
// Pressure control: waves_per_eu(2,2) pins the 256-VGPR budget;
// sched_barrier(0) every 8 K-groups caps hoisted hv regs at 32;
// unroll 1 on the t-loop. ONE barrier per step.
// ---------------------------------------------------------------------------
__global__ __launch_bounds__(512)
__attribute__((amdgpu_waves_per_eu(2, 2)))
void rnn_scan(const float* __restrict__ A,
              const float* __restrict__ xB,
              float* __restrict__ hs) {
    __shared__ __align__(16) float hbuf[2][H_DIM];
    const int tid = threadIdx.x;
    const int w   = tid >> 6;          // wave 0..7
    const int lane = tid & 63;
    const int cc  = lane >> 2;         // 0..15
    const int g   = lane & 3;          // k-slice 0..3
    const int c0  = w * 16 + cc;       // first owned column
    const int c1  = c0 + 128;          // second owned column
    const int b = blockIdx.x;

#define ADECL(K) float4 a##K##_0, a##K##_1;
    REP16(ADECL)
#undef ADECL
    // load in the XOR-permuted k order to match the swizzled h reads
#define ALOAD(K) { const int row = 64 * g + 4 * ((K) ^ g); \
    a##K##_0 = make_float4(A[(row + 0) * H_DIM + c0], A[(row + 1) * H_DIM + c0], \
                           A[(row + 2) * H_DIM + c0], A[(row + 3) * H_DIM + c0]); \
    a##K##_1 = make_float4(A[(row + 0) * H_DIM + c1], A[(row + 1) * H_DIM + c1], \
                           A[(row + 2) * H_DIM + c1], A[(row + 3) * H_DIM + c1]); }
    REP16(ALOAD)
#undef ALOAD
#define APIN(K) asm volatile("" : "+v"(a##K##_0.x), "+v"(a##K##_0.y), "+v"(a##K##_0.z), "+v"(a##K##_0.w), \
                                  "+v"(a##K##_1.x), "+v"(a##K##_1.y), "+v"(a##K##_1.z), "+v"(a##K##_1.w));
    REP16(APIN)
#undef APIN

    const long base = (long)b * T_LEN * H_DIM;
    const int jw = (g == 0) ? c0 : c1;             // column written by this lane (g<2)
    const float* __restrict__ xbp = xB + base + jw;
    float* __restrict__ hp = hs + base + jw;
    const uintptr_t lds0 = (uintptr_t)&hbuf[0][0];
    const uintptr_t myrd = lds0 + (uintptr_t)(272 * g);   // 256g + 16g (disjoint bits)

    // t = 0: h_prev = 0 -> h = tanh(xb)
    float xbn = 0.f;
    if (g < 2) {
        float hn0 = fast_tanh(xbp[0]);
        hbuf[0][jw] = hn0;
        hp[0] = hn0;
        xbn = xbp[H_DIM];   // prefetch t=1
    }
    __syncthreads();

#pragma unroll 1
    for (int t = 1; t < T_LEN; ++t) {
        const uintptr_t hb = myrd + (uintptr_t)(((t + 1) & 1) * (H_DIM * 4));
        // issue next-step xb prefetch first, then pin it above the FMA wall
        float xbn2 = 0.f;
        const int tn = (t + 1 < T_LEN) ? t + 1 : t;
        if (g < 2) xbn2 = xbp[(long)tn * H_DIM];
        __builtin_amdgcn_sched_barrier(0);

        float y00 = 0.f, y01 = 0.f, y02 = 0.f, y03 = 0.f;
        float y10 = 0.f, y11 = 0.f, y12 = 0.f, y13 = 0.f;
#define FMA4(K) { const float4 hv = *(const float4*)(hb ^ (uintptr_t)(16 * (K))); \
        y00 = fmaf(hv.x, a##K##_0.x, y00); \
        y01 = fmaf(hv.y, a##K##_0.y, y01); \
        y02 = fmaf(hv.z, a##K##_0.z, y02); \
        y03 = fmaf(hv.w, a##K##_0.w, y03); \
        y10 = fmaf(hv.x, a##K##_1.x, y10); \
        y11 = fmaf(hv.y, a##K##_1.y, y11); \
        y12 = fmaf(hv.z, a##K##_1.z, y12); \
        y13 = fmaf(hv.w, a##K##_1.w, y13); }
        REP8A(FMA4)
        __builtin_amdgcn_sched_barrier(0);   // cap hoisted hv pressure
        REP8B(FMA4)
#undef FMA4
        float y0 = (y00 + y01) + (y02 + y03);
        float y1 = (y10 + y11) + (y12 + y13);
        // combine the 4 k-slices (lane bits 0-1 of the quad)
        y0 += __shfl_xor(y0, 1); y1 += __shfl_xor(y1, 1);
        y0 += __shfl_xor(y0, 2); y1 += __shfl_xor(y1, 2);

        if (g < 2) {
            float y = ((g == 0) ? y0 : y1) + xbn;
            float hn = fast_tanh(y);
            hbuf[t & 1][jw] = hn;
            hp[(long)t * H_DIM] = hn;
        }
        xbn = xbn2;
        __syncthreads();   // h_t in LDS visible to all waves for t+1
    }
}

// ---------------------------------------------------------------------------
// Phase 3: out[r][j] = sum_k hs[r][k] * C[k][j]  (R2 version, in place)
// ---------------------------------------------------------------------------
__global__ __launch_bounds__(256) void out_proj(float* __restrict__ hs_out,
                                                const float* __restrict__ C) {
    __shared__ float4 ht[ROWS][H_DIM / 4 + 1];
    const int tid = threadIdx.x;
    const int j = tid;
    const long r0 = (long)blockIdx.x * ROWS;

    const float4* hg = (const float4*)(hs_out + r0 * H_DIM);
#pragma unroll
    for (int i = 0; i < 8; ++i) {
        int f = tid + i * 256;
        int rr = f >> 6;
        int kg = f & 63;
        ht[rr][kg] = hg[rr * 64 + kg];
    }
    __syncthreads();

    float acc[ROWS];
#pragma unroll
    for (int r = 0; r < ROWS; ++r) acc[r] = 0.f;

    for (int k = 0; k < H_DIM; k += 4) {
        float w0 = C[(k + 0) * H_DIM + j];
        float w1 = C[(k + 1) * H_DIM + j];
        float w2 = C[(k + 2) * H_DIM + j];
        float w3 = C[(k + 3) * H_DIM + j];
#pragma unroll
        for (int r = 0; r < ROWS; ++r) {
            float4 hv = ht[r][k >> 2];
            acc[r] = fmaf(hv.x, w0, acc[r]);
            acc[r] = fmaf(hv.y, w1, acc[r]);
            acc[r] = fmaf(hv.z, w2, acc[r]);
            acc[r] = fmaf(hv.w, w3, acc[r]);
        }
    }
#pragma unroll
    for (int r = 0; r < ROWS; ++r)
        hs_out[(r0 + r) * H_DIM + j] = acc[r];
}

// ---------------------------------------------------------------------------
extern "C" void kernel_launch(void* const* d_in, const int* in_sizes, int n_in,
                              void* d_out, int out_size, void* d_ws, size_t ws_size,
                              hipStream_t stream) {
    const float* x  = (const float*)d_in[0];
    const float* A  = (const float*)d_in[1];
    const float* Bm = (const float*)d_in[2];
    const float* C  = (const float*)d_in[3];
    float* out = (float*)d_out;
    float* xB  = (float*)d_ws;   // 64 MB scratch

    const int R = B_SZ * T_LEN;  // 65536 rows

    xb_proj<<<R / ROWS, 256, 0, stream>>>(x, Bm, xB);
    rnn_scan<<<B_SZ, 512, 0, stream>>>(A, xB, out);
    out_proj<<<R / ROWS, 256, 0, stream>>>(out, C);
}